// Round 1
// 174.224 us; speedup vs baseline: 1.0102x; 1.0102x over previous
//
#include <hip/hip_runtime.h>

// Problem: x [64,128,56,56] fp32; act_codes [C*H*W] int32 in [0,6).
// out[b, n] = act[act_codes[n]](x[b, n]) with n over C*H*W = 401408.
// N/4 = 100352 = 392 * 256 exactly -> exact 2D grid, no bounds checks.
//
// R1: VALU-bound per rocprof (VALUBusy 73.5%, hbm 32.5% peak). The three
// fp32 divides each expanded to the ~10-instr IEEE div sequence. Replace
// with v_rcp_f32 (__builtin_amdgcn_rcpf, ~1 ulp); fold exp constants into
// native v_exp_f32 (exp2); non-temporal stores so the out-stream doesn't
// evict x from the 256 MB Infinity Cache between iterations.

#define N4 100352   // (128*56*56)/4
#define GX 392      // N4 / 256
#define GY 64       // batch

typedef float  f32x4 __attribute__((ext_vector_type(4)));

__device__ __forceinline__ float apply_act(float x, int c) {
    const float L2E = 1.4426950408889634f;   // log2(e)

    // shared transcendental core (all native ops)
    float ax = fabsf(x);
    float e1 = __builtin_amdgcn_exp2f(-L2E * ax);   // exp(-|x|) in (0,1]
    float e2 = e1 * e1;                             // exp(-2|x|)
    float r1 = __builtin_amdgcn_rcpf(1.f + e1);     // v_rcp_f32, ~1 ulp
    float r2 = __builtin_amdgcn_rcpf(1.f + e2);
    bool pos = x >= 0.f;

    float relu  = fmaxf(x, 0.f);                    // c == 0
    float sig   = pos ? r1 : e1 * r1;               // c == 1  (sign-folded, stable)
    float th_a  = (1.f - e2) * r2;                  // tanh(|x|)
    float th    = pos ? th_a : -th_a;               // c == 2
    float elu   = pos ? x : (e1 - 1.f);             // c == 3  (x<0 -> exp(x)-1)
    float leaky = pos ? x : 0.01f * x;              // c == 4

    // c == 5: jax.nn.gelu default approximate=True (tanh formula)
    // u = sqrt(2/pi) * (x + 0.044715 x^3) = x * (0.7978845608 + 0.0356774081 x^2)
    float u  = x * fmaf(0.0356774081f, x * x, 0.7978845608f);
    float au = fabsf(u);
    float e3 = __builtin_amdgcn_exp2f(-2.f * L2E * au);  // exp(-2|u|)
    float t3 = (1.f - e3) * __builtin_amdgcn_rcpf(1.f + e3);
    float tg = (u >= 0.f) ? t3 : -t3;
    float gelu = 0.5f * x * (1.f + tg);

    float r = relu;
    r = (c == 1) ? sig   : r;
    r = (c == 2) ? th    : r;
    r = (c == 3) ? elu   : r;
    r = (c == 4) ? leaky : r;
    r = (c == 5) ? gelu  : r;
    return r;
}

__global__ __launch_bounds__(256) void act_select_kernel(
    const f32x4* __restrict__ x,
    const int4*  __restrict__ codes,
    f32x4*       __restrict__ out) {
    int n   = blockIdx.x * 256 + threadIdx.x;   // [0, N4)
    int idx = blockIdx.y * N4 + n;              // max 6,422,527 < 2^31

    f32x4 v = x[idx];
    int4  c = codes[n];                         // L2/L3-resident after first batch row

    f32x4 o;
    o.x = apply_act(v.x, c.x);
    o.y = apply_act(v.y, c.y);
    o.z = apply_act(v.z, c.z);
    o.w = apply_act(v.w, c.w);

    // out is write-once, never re-read: bypass caches so x stays L3-resident
    __builtin_nontemporal_store(o, &out[idx]);
}

extern "C" void kernel_launch(void* const* d_in, const int* in_sizes, int n_in,
                              void* d_out, int out_size, void* d_ws, size_t ws_size,
                              hipStream_t stream) {
    const f32x4* x     = (const f32x4*)d_in[0];
    const int4*  codes = (const int4*)d_in[1];
    f32x4*       out   = (f32x4*)d_out;

    dim3 grid(GX, GY);
    act_select_kernel<<<grid, 256, 0, stream>>>(x, codes, out);
}